// Round 9
// baseline (390.324 us; speedup 1.0000x reference)
//
#include <hip/hip_runtime.h>
#include <hip/hip_bf16.h>

// SinkhornOT, split-kernel version for MI355X (gfx950).
// Kernel A (gemm_cdist, 1 block = 1 batch elem, 512 thr, 33KB LDS, 6 barriers,
//           4 blocks/CU):
//   X=[q;r] (64x256) -> bf16 fragment-major LDS (single in-place buffer)
//   -> H=relu(X@W1+b1) (MFMA, in-place) -> Q=H@W2+b2 (in-place)
//   -> C via MFMA: C^2 = nq + nr - 2 q.r  (waves 0-3 dot tiles, waves 4-7 norms)
// r9: wave tiling 64rx32c -> 32rx64c. LDS census said A-re-reads (each wave
// reading the whole 32KB A tile) made LDS BW co-dominant (~8.6K of 17K cyc
// @85B/cyc); halving A-reads (2 ds_read_b128/ki) trades for 2x B L2 loads.
// LESSON (r5/r6): no HBM prefetch data held in VGPRs across a GEMM phase
// (spills to scratch). LESSON (r8): VGPR count is compiler-chosen, not
// cap-bound; don't trade occupancy for a register budget it won't use.
// Kernel B (sinkhorn_mesh, 1 wave = 1 problem, no barriers, wave-sync LDS):
//   15 log-domain Sinkhorn iters + T + 3 mesh iters + cost/sim + T out.
// prep_w packs W1/W2 as bf16 MFMA B-fragments (k-map k_local = 8g+j, used
// consistently for A and B so the bijection cancels; HW-validated r1-r8).

typedef unsigned short u16;
typedef short short8 __attribute__((ext_vector_type(8)));
typedef float f32x4  __attribute__((ext_vector_type(4)));

#define MFMA(a, b, c) __builtin_amdgcn_mfma_f32_16x16x32_bf16((a), (b), (c), 0, 0, 0)

static __device__ __forceinline__ u16 f2bf(float f) {  // native RNE cvt (pairs fuse to v_cvt_pk_bf16_f32)
  __hip_bfloat16 h = __float2bfloat16(f);
  return __builtin_bit_cast(u16, h);
}
static __device__ __forceinline__ float bf2f(u16 h) {
  return __uint_as_float(((unsigned)h) << 16);
}

// ---------------- W fragment prep ----------------
// lane l = g*16 + (n&15) holds B[k = ki*32 + 8g + j][col = 16*ctg + (n&15)]
// ws u16 layout: mat*65536 + ((ki*16 + ctg)*64 + lane)*8 + j   (256 KB total)
__global__ __launch_bounds__(256) void prep_w(const float* __restrict__ W1,
                                              const float* __restrict__ W2,
                                              u16* __restrict__ ws) {
  int id = blockIdx.x * 256 + threadIdx.x;  // 0..131071
  int mat = id >> 16;
  int e = id & 65535;   // e = k*256 + n
  int k = e >> 8, n = e & 255;
  float wv = (mat ? W2 : W1)[e];
  int ki = k >> 5, kl = k & 31;
  int g = kl >> 3, j = kl & 7;
  int lane = g * 16 + (n & 15);
  int ctg = n >> 4;
  ws[mat * 65536 + ((((ki * 16 + ctg) * 64 + lane) << 3) | j)] = f2bf(wv);
}

// ---------------- kernel A ----------------
struct __align__(16) SMemA {
  u16 F[16384];    // 32KB single buffer: X frags -> H frags -> Q frags (in place)
  float nrm[64];   // row norms of Q (0-31 q, 32-63 r)
};

// 64x256 @ 256x256, wave tile 32 rows x 64 cols:
//   rh = w&1 (rows 32rh..32rh+31, rt tiles {2rh,2rh+1}),
//   cq = w>>1 (cols 64cq..64cq+63, B records 4cq..4cq+3 per ki).
// Per ki: 2 A ds_read_b128 + 4 B global 16B + 8 MFMA. acc[2][4] = 32 VGPR.
static __device__ __forceinline__ void gemm_frag(const u16* __restrict__ Af,
                                                 const u16* __restrict__ wf,
                                                 int rh, int cq, int lane,
                                                 f32x4 acc[2][4]) {
#pragma unroll
  for (int rt = 0; rt < 2; ++rt)
#pragma unroll
    for (int ct = 0; ct < 4; ++ct) acc[rt][ct] = f32x4{0.f, 0.f, 0.f, 0.f};
  __builtin_amdgcn_s_setprio(1);
#pragma unroll
  for (int ki = 0; ki < 8; ++ki) {
    const u16* bp = wf + (((ki * 16 + 4 * cq) * 64 + lane) << 3);
    short8 b0 = *reinterpret_cast<const short8*>(bp);         // 16B/lane, coalesced
    short8 b1 = *reinterpret_cast<const short8*>(bp + 512);
    short8 b2 = *reinterpret_cast<const short8*>(bp + 1024);
    short8 b3 = *reinterpret_cast<const short8*>(bp + 1536);
    short8 a0 = *reinterpret_cast<const short8*>(
        Af + (((ki * 4 + 2 * rh) * 64 + lane) << 3));
    short8 a1 = *reinterpret_cast<const short8*>(
        Af + (((ki * 4 + 2 * rh + 1) * 64 + lane) << 3));
    acc[0][0] = MFMA(a0, b0, acc[0][0]);
    acc[0][1] = MFMA(a0, b1, acc[0][1]);
    acc[0][2] = MFMA(a0, b2, acc[0][2]);
    acc[0][3] = MFMA(a0, b3, acc[0][3]);
    acc[1][0] = MFMA(a1, b0, acc[1][0]);
    acc[1][1] = MFMA(a1, b1, acc[1][1]);
    acc[1][2] = MFMA(a1, b2, acc[1][2]);
    acc[1][3] = MFMA(a1, b3, acc[1][3]);
  }
  __builtin_amdgcn_s_setprio(0);
}

__global__ __launch_bounds__(512, 8) void gemm_cdist(
    const float* __restrict__ slots_q, const float* __restrict__ slots_r,
    const float* __restrict__ b1, const float* __restrict__ b2,
    const u16* __restrict__ ws, float* __restrict__ CO) {
  __shared__ SMemA sm;
  const int tid = threadIdx.x, b = blockIdx.x;
  const int w = tid >> 6, lane = tid & 63, g = lane >> 4, ln = lane & 15;
  const int rh = w & 1, cq = w >> 1;

  // ---- stage X fragment-major: slot s = (ki*4+rt)*64 + g*16 + ln ----
  {
    const float* srcq = slots_q + (size_t)b * 8192;
    const float* srcr = slots_r + (size_t)b * 8192;
#pragma unroll
    for (int ii = 0; ii < 4; ++ii) {
      int s = tid + ii * 512;  // 0..2047
      int ki = s >> 8, rt = (s >> 6) & 3, sg = (s >> 4) & 3, sln = s & 15;
      int row = rt * 16 + sln;
      const float* src = (row < 32) ? (srcq + row * 256) : (srcr + (row - 32) * 256);
      int k0 = ki * 32 + sg * 8;
      float4 v0 = *reinterpret_cast<const float4*>(src + k0);
      float4 v1 = *reinterpret_cast<const float4*>(src + k0 + 4);
      short8 o;
      o[0] = (short)f2bf(v0.x); o[1] = (short)f2bf(v0.y);
      o[2] = (short)f2bf(v0.z); o[3] = (short)f2bf(v0.w);
      o[4] = (short)f2bf(v1.x); o[5] = (short)f2bf(v1.y);
      o[6] = (short)f2bf(v1.z); o[7] = (short)f2bf(v1.w);
      *reinterpret_cast<short8*>(&sm.F[s << 3]) = o;  // contiguous, conflict-free
    }
  }
  float bva[4], bvb[4];  // biases for this wave's 4 col-tiles (static idx after unroll)
#pragma unroll
  for (int ct = 0; ct < 4; ++ct) {
    bva[ct] = b1[64 * cq + 16 * ct + ln];
    bvb[ct] = b2[64 * cq + 16 * ct + ln];
  }
  __syncthreads();

  f32x4 acc[2][4];
  // ---- GEMM1: H = relu(X@W1 + b1) ----
  gemm_frag(sm.F, ws, rh, cq, lane, acc);
  __syncthreads();  // all X reads complete before overwriting F with H
#pragma unroll
  for (int ct = 0; ct < 4; ++ct) {
    // output col n = 64cq + 16ct + ln  ->  H A-frag coords:
    int ki2 = 2 * cq + (ct >> 1);
    int g2 = 2 * (ct & 1) + (ln >> 3);
#pragma unroll
    for (int rt = 0; rt < 2; ++rt) {
      int rtg = 2 * rh + rt;  // row tile (rows rtg*16 + 4g + ri)
#pragma unroll
      for (int ri = 0; ri < 4; ++ri) {
        int lane2 = g2 * 16 + 4 * g + ri;
        sm.F[(((ki2 * 4 + rtg) * 64 + lane2) << 3) | (ln & 7)] =
            f2bf(fmaxf(acc[rt][ct][ri] + bva[ct], 0.0f));
      }
    }
  }
  __syncthreads();

  // ---- GEMM2: Q = H@W2 + b2 ----
  gemm_frag(sm.F, ws + 65536, rh, cq, lane, acc);
  __syncthreads();  // all H reads complete before overwriting F with Q
#pragma unroll
  for (int ct = 0; ct < 4; ++ct) {
    int ki2 = 2 * cq + (ct >> 1);
    int g2 = 2 * (ct & 1) + (ln >> 3);
#pragma unroll
    for (int rt = 0; rt < 2; ++rt) {
      int rtg = 2 * rh + rt;
#pragma unroll
      for (int ri = 0; ri < 4; ++ri) {
        int lane2 = g2 * 16 + 4 * g + ri;
        sm.F[(((ki2 * 4 + rtg) * 64 + lane2) << 3) | (ln & 7)] =
            f2bf(acc[rt][ct][ri] + bvb[ct]);
      }
    }
  }
  __syncthreads();

  // ---- C^2 = nq + nr - 2 q.r : waves 0-3 dot tiles (MFMA), waves 4-7 norms ----
  f32x4 dacc = f32x4{0.f, 0.f, 0.f, 0.f};
  if (w < 4) {
    const int mt = w >> 1, nt = w & 1;  // q row-tile, r row-tile
    __builtin_amdgcn_s_setprio(1);
#pragma unroll
    for (int ki = 0; ki < 8; ++ki) {
      // A = q rows tile mt; B = r rows tile (2+nt) — A-frag of r IS B-frag of r^T
      short8 aq = *reinterpret_cast<const short8*>(
          &sm.F[(((ki * 4 + mt) * 64 + lane) << 3)]);
      short8 br = *reinterpret_cast<const short8*>(
          &sm.F[(((ki * 4 + 2 + nt) * 64 + lane) << 3)]);
      dacc = MFMA(aq, br, dacc);
    }
    __builtin_amdgcn_s_setprio(0);
  } else {
    const int t = w - 4;  // row-tile t: rows 16t .. 16t+15
    float s = 0.f;
#pragma unroll
    for (int ki = 0; ki < 8; ++ki) {
      short8 v = *reinterpret_cast<const short8*>(
          &sm.F[(((ki * 4 + t) * 64 + lane) << 3)]);
#pragma unroll
      for (int i = 0; i < 8; ++i) {
        float f = bf2f((u16)v[i]);
        s = fmaf(f, f, s);
      }
    }
    s += __shfl_xor(s, 16);  // reduce over k-groups g (same row, different k slice)
    s += __shfl_xor(s, 32);
    if (lane < 16) sm.nrm[t * 16 + lane] = s;
  }
  __syncthreads();

  if (w < 4) {
    const int mt = w >> 1, nt = w & 1;
    float* Cp = CO + (size_t)b * 1024;
#pragma unroll
    for (int ri = 0; ri < 4; ++ri) {
      int k = mt * 16 + 4 * g + ri;   // D layout: row = 4g+ri, col = ln
      int m = nt * 16 + ln;
      float sq = sm.nrm[k] + sm.nrm[32 + m] - 2.0f * dacc[ri];
      Cp[k * 32 + m] = sqrtf(fmaxf(sq, 0.0f));
    }
  }
}

// ---------------- kernel B: 1 wave = 1 problem, no barriers ----------------
__global__ __launch_bounds__(256, 4) void sinkhorn_mesh(
    const float* __restrict__ CO, float* __restrict__ simO,
    float* __restrict__ TO, float* __restrict__ costO, int Bn) {
  __shared__ float Wl[4][32 * 33];
  __shared__ float ABl[4][64];
  const int wv = threadIdx.x >> 6, lane = threadIdx.x & 63;
  const int p = blockIdx.x * 4 + wv;
  if (p >= Bn) return;
  const int h = lane >> 5, q = lane & 31;  // q = row k (row ops) / col (col ops)
  float* Wm = Wl[wv];
  float* LA = ABl[wv];
  float* LB = ABl[wv] + 32;
  const float* Cp = CO + (size_t)p * 1024;

  // lane holds row q cols [16h,16h+16) in lkr, col q rows [16h,16h+16) in lkc
  float lkr[16], lkc[16];
#pragma unroll
  for (int jj = 0; jj < 4; ++jj) {
    float4 v = *reinterpret_cast<const float4*>(Cp + q * 32 + h * 16 + jj * 4);
    int base = q * 33 + h * 16 + jj * 4;
    Wm[base + 0] = v.x; Wm[base + 1] = v.y; Wm[base + 2] = v.z; Wm[base + 3] = v.w;
    lkr[jj * 4 + 0] = -20.f * v.x; lkr[jj * 4 + 1] = -20.f * v.y;
    lkr[jj * 4 + 2] = -20.f * v.z; lkr[jj * 4 + 3] = -20.f * v.w;
  }
  LB[q] = 0.0f;
  __builtin_amdgcn_wave_barrier();
#pragma unroll
  for (int j = 0; j < 16; ++j) lkc[j] = -20.f * Wm[(h * 16 + j) * 33 + q];

  for (int it = 0; it < 15; ++it) {
    float v[16], mx, s;
#pragma unroll
    for (int j = 0; j < 16; ++j) v[j] = lkr[j] + LB[h * 16 + j];
    mx = v[0];
#pragma unroll
    for (int j = 1; j < 16; ++j) mx = fmaxf(mx, v[j]);
    mx = fmaxf(mx, __shfl_xor(mx, 32));
    s = 0.f;
#pragma unroll
    for (int j = 0; j < 16; ++j) s += __expf(v[j] - mx);
    s += __shfl_xor(s, 32);
    LA[q] = -(mx + __logf(s));  // both halves write identical value
    __builtin_amdgcn_wave_barrier();
#pragma unroll
    for (int j = 0; j < 16; ++j) v[j] = lkc[j] + LA[h * 16 + j];
    mx = v[0];
#pragma unroll
    for (int j = 1; j < 16; ++j) mx = fmaxf(mx, v[j]);
    mx = fmaxf(mx, __shfl_xor(mx, 32));
    s = 0.f;
#pragma unroll
    for (int j = 0; j < 16; ++j) s += __expf(v[j] - mx);
    s += __shfl_xor(s, 32);
    LB[q] = -(mx + __logf(s));
    __builtin_amdgcn_wave_barrier();
  }

  // T = exp(log_K + la + lb), row view
  float t[16];
  {
    float la = LA[q];
#pragma unroll
    for (int j = 0; j < 16; ++j) t[j] = __expf(lkr[j] + la + LB[h * 16 + j]);
  }

  // mesh: T=T^2; row-norm; col-norm (via LDS transpose; wave-sync only)
  for (int mi = 0; mi < 3; ++mi) {
    float s = 0.f;
#pragma unroll
    for (int j = 0; j < 16; ++j) { t[j] *= t[j]; s += t[j]; }
    s += __shfl_xor(s, 32);
    float inv = 1.0f / (s + 1e-8f);
#pragma unroll
    for (int j = 0; j < 16; ++j) Wm[q * 33 + h * 16 + j] = t[j] * inv;
    __builtin_amdgcn_wave_barrier();
#pragma unroll
    for (int j = 0; j < 16; ++j) t[j] = Wm[(h * 16 + j) * 33 + q];  // col view
    s = 0.f;
#pragma unroll
    for (int j = 0; j < 16; ++j) s += t[j];
    s += __shfl_xor(s, 32);
    inv = 1.0f / (s + 1e-8f);
#pragma unroll
    for (int j = 0; j < 16; ++j) Wm[(h * 16 + j) * 33 + q] = t[j] * inv;
    __builtin_amdgcn_wave_barrier();
#pragma unroll
    for (int j = 0; j < 16; ++j) t[j] = Wm[q * 33 + h * 16 + j];  // back to rows
  }

  // cost = sum(T*C); C = -lkr/20
  float pp = 0.f;
#pragma unroll
  for (int j = 0; j < 16; ++j) pp = fmaf(t[j], -0.05f * lkr[j], pp);
  pp += __shfl_xor(pp, 1); pp += __shfl_xor(pp, 2); pp += __shfl_xor(pp, 4);
  pp += __shfl_xor(pp, 8); pp += __shfl_xor(pp, 16); pp += __shfl_xor(pp, 32);
  if (lane == 0) {
    costO[p] = pp;
    simO[p] = 1.0f / (1.0f + __expf(pp));  // sigmoid(-cost)
  }
  // T out (coalesced float4 from row view)
#pragma unroll
  for (int jj = 0; jj < 4; ++jj) {
    float4 o;
    o.x = t[jj * 4 + 0]; o.y = t[jj * 4 + 1];
    o.z = t[jj * 4 + 2]; o.w = t[jj * 4 + 3];
    *reinterpret_cast<float4*>(TO + (size_t)p * 1024 + q * 32 + h * 16 + jj * 4) = o;
  }
}

extern "C" void kernel_launch(void* const* d_in, const int* in_sizes, int n_in,
                              void* d_out, int out_size, void* d_ws, size_t ws_size,
                              hipStream_t stream) {
  const float* slots_q = (const float*)d_in[0];
  const float* slots_r = (const float*)d_in[1];
  const float* W1 = (const float*)d_in[2];
  const float* b1 = (const float*)d_in[3];
  const float* W2 = (const float*)d_in[4];
  const float* b2 = (const float*)d_in[5];
  float* out = (float*)d_out;

  const int Bn = in_sizes[0] / 8192;  // 32*256 per batch element
  u16* ws = (u16*)d_ws;               // 256 KB W fragments

  prep_w<<<dim3(512), dim3(256), 0, stream>>>(W1, W2, ws);

  float* simO = out;
  float* TO = out + Bn;
  float* CO = TO + (size_t)Bn * 1024;
  float* costO = CO + (size_t)Bn * 1024;

  gemm_cdist<<<dim3(Bn), dim3(512), 0, stream>>>(slots_q, slots_r, b1, b2, ws, CO);
  sinkhorn_mesh<<<dim3((Bn + 3) / 4), dim3(256), 0, stream>>>(CO, simO, TO, costO, Bn);
}

// Round 10
// 327.496 us; speedup vs baseline: 1.1918x; 1.1918x over previous
//
#include <hip/hip_runtime.h>
#include <hip/hip_bf16.h>

// SinkhornOT, split-kernel version for MI355X (gfx950).
// Kernel A (gemm_cdist, 1 block = 1 batch elem, 512 thr, 33KB LDS, 6 barriers,
//           4 blocks/CU):
//   X=[q;r] (64x256) -> bf16 fragment-major LDS (single in-place buffer)
//   -> H=relu(X@W1+b1) (MFMA, in-place) -> Q=H@W2+b2 (in-place)
//   -> C via MFMA: C^2 = nq + nr - 2 q.r  (waves 0-3 dot tiles, waves 4-7 norms)
// r10: keep r9's 32rx64c wave tiling (halves A LDS reads: 2 ds_read_b128/ki)
// but fix the r9 spill: (a) B-frags loaded as two pairs reusing 2 regs
// (peak live ~52 < 64-VGPR cap of (512,8)), (b) bias loads deferred to the
// epilogues instead of pinned across the kernel.
// LESSONS: r5/r6 - no HBM data held in VGPRs across a GEMM phase (spill).
// r8 - VGPR count is compiler-chosen; don't trade occupancy for unused budget.
// r9 - at (512,8) every phase must fit 64 VGPR; size the live set explicitly.
// Kernel B (sinkhorn_mesh, 1 wave = 1 problem, no barriers, wave-sync LDS).
// prep_w packs W1/W2 as bf16 MFMA B-fragments (k-map k_local = 8g+j, used
// consistently for A and B so the bijection cancels; HW-validated r1-r9).

typedef unsigned short u16;
typedef short short8 __attribute__((ext_vector_type(8)));
typedef float f32x4  __attribute__((ext_vector_type(4)));

#define MFMA(a, b, c) __builtin_amdgcn_mfma_f32_16x16x32_bf16((a), (b), (c), 0, 0, 0)

static __device__ __forceinline__ u16 f2bf(float f) {  // native RNE cvt (pairs fuse to v_cvt_pk_bf16_f32)
  __hip_bfloat16 h = __float2bfloat16(f);
  return __builtin_bit_cast(u16, h);
}
static __device__ __forceinline__ float bf2f(u16 h) {
  return __uint_as_float(((unsigned)h) << 16);
}

// ---------------- W fragment prep ----------------
// lane l = g*16 + (n&15) holds B[k = ki*32 + 8g + j][col = 16*ctg + (n&15)]
// ws u16 layout: mat*65536 + ((ki*16 + ctg)*64 + lane)*8 + j   (256 KB total)
__global__ __launch_bounds__(256) void prep_w(const float* __restrict__ W1,
                                              const float* __restrict__ W2,
                                              u16* __restrict__ ws) {
  int id = blockIdx.x * 256 + threadIdx.x;  // 0..131071
  int mat = id >> 16;
  int e = id & 65535;   // e = k*256 + n
  int k = e >> 8, n = e & 255;
  float wv = (mat ? W2 : W1)[e];
  int ki = k >> 5, kl = k & 31;
  int g = kl >> 3, j = kl & 7;
  int lane = g * 16 + (n & 15);
  int ctg = n >> 4;
  ws[mat * 65536 + ((((ki * 16 + ctg) * 64 + lane) << 3) | j)] = f2bf(wv);
}

// ---------------- kernel A ----------------
struct __align__(16) SMemA {
  u16 F[16384];    // 32KB single buffer: X frags -> H frags -> Q frags (in place)
  float nrm[64];   // row norms of Q (0-31 q, 32-63 r)
};

// 64x256 @ 256x256, wave tile 32 rows x 64 cols:
//   rh = w&1 (rows 32rh..32rh+31), cq = w>>1 (cols 64cq..64cq+63).
// Per ki: 2 A ds_read_b128 + B in two reg-reused pairs + 8 MFMA.
static __device__ __forceinline__ void gemm_frag(const u16* __restrict__ Af,
                                                 const u16* __restrict__ wf,
                                                 int rh, int cq, int lane,
                                                 f32x4 acc[2][4]) {
#pragma unroll
  for (int rt = 0; rt < 2; ++rt)
#pragma unroll
    for (int ct = 0; ct < 4; ++ct) acc[rt][ct] = f32x4{0.f, 0.f, 0.f, 0.f};
  __builtin_amdgcn_s_setprio(1);
#pragma unroll
  for (int ki = 0; ki < 8; ++ki) {
    const u16* bp = wf + (((ki * 16 + 4 * cq) * 64 + lane) << 3);
    short8 a0 = *reinterpret_cast<const short8*>(
        Af + (((ki * 4 + 2 * rh) * 64 + lane) << 3));
    short8 a1 = *reinterpret_cast<const short8*>(
        Af + (((ki * 4 + 2 * rh + 1) * 64 + lane) << 3));
    {
      short8 bx = *reinterpret_cast<const short8*>(bp);        // 16B/lane, coalesced
      short8 by = *reinterpret_cast<const short8*>(bp + 512);
      acc[0][0] = MFMA(a0, bx, acc[0][0]);
      acc[1][0] = MFMA(a1, bx, acc[1][0]);
      acc[0][1] = MFMA(a0, by, acc[0][1]);
      acc[1][1] = MFMA(a1, by, acc[1][1]);
    }
    {
      short8 bx = *reinterpret_cast<const short8*>(bp + 1024);  // reg reuse
      short8 by = *reinterpret_cast<const short8*>(bp + 1536);
      acc[0][2] = MFMA(a0, bx, acc[0][2]);
      acc[1][2] = MFMA(a1, bx, acc[1][2]);
      acc[0][3] = MFMA(a0, by, acc[0][3]);
      acc[1][3] = MFMA(a1, by, acc[1][3]);
    }
  }
  __builtin_amdgcn_s_setprio(0);
}

__global__ __launch_bounds__(512, 8) void gemm_cdist(
    const float* __restrict__ slots_q, const float* __restrict__ slots_r,
    const float* __restrict__ b1, const float* __restrict__ b2,
    const u16* __restrict__ ws, float* __restrict__ CO) {
  __shared__ SMemA sm;
  const int tid = threadIdx.x, b = blockIdx.x;
  const int w = tid >> 6, lane = tid & 63, g = lane >> 4, ln = lane & 15;
  const int rh = w & 1, cq = w >> 1;

  // ---- stage X fragment-major: slot s = (ki*4+rt)*64 + g*16 + ln ----
  {
    const float* srcq = slots_q + (size_t)b * 8192;
    const float* srcr = slots_r + (size_t)b * 8192;
#pragma unroll
    for (int ii = 0; ii < 4; ++ii) {
      int s = tid + ii * 512;  // 0..2047
      int ki = s >> 8, rt = (s >> 6) & 3, sg = (s >> 4) & 3, sln = s & 15;
      int row = rt * 16 + sln;
      const float* src = (row < 32) ? (srcq + row * 256) : (srcr + (row - 32) * 256);
      int k0 = ki * 32 + sg * 8;
      float4 v0 = *reinterpret_cast<const float4*>(src + k0);
      float4 v1 = *reinterpret_cast<const float4*>(src + k0 + 4);
      short8 o;
      o[0] = (short)f2bf(v0.x); o[1] = (short)f2bf(v0.y);
      o[2] = (short)f2bf(v0.z); o[3] = (short)f2bf(v0.w);
      o[4] = (short)f2bf(v1.x); o[5] = (short)f2bf(v1.y);
      o[6] = (short)f2bf(v1.z); o[7] = (short)f2bf(v1.w);
      *reinterpret_cast<short8*>(&sm.F[s << 3]) = o;  // contiguous, conflict-free
    }
  }
  __syncthreads();

  f32x4 acc[2][4];
  // ---- GEMM1: H = relu(X@W1 + b1) ----
  gemm_frag(sm.F, ws, rh, cq, lane, acc);
  // bias loads issued here (after MFMA loop, hidden under barrier latency)
  float bva0 = b1[64 * cq + ln],      bva1 = b1[64 * cq + 16 + ln];
  float bva2 = b1[64 * cq + 32 + ln], bva3 = b1[64 * cq + 48 + ln];
  __syncthreads();  // all X reads complete before overwriting F with H
#pragma unroll
  for (int ct = 0; ct < 4; ++ct) {
    float bv = (ct == 0) ? bva0 : (ct == 1) ? bva1 : (ct == 2) ? bva2 : bva3;
    // output col n = 64cq + 16ct + ln  ->  A-frag coords (verified r9, passed):
    int ki2 = 2 * cq + (ct >> 1);
    int g2 = 2 * (ct & 1) + (ln >> 3);
#pragma unroll
    for (int rt = 0; rt < 2; ++rt) {
      int rtg = 2 * rh + rt;  // row tile (rows rtg*16 + 4g + ri)
#pragma unroll
      for (int ri = 0; ri < 4; ++ri) {
        int lane2 = g2 * 16 + 4 * g + ri;
        sm.F[(((ki2 * 4 + rtg) * 64 + lane2) << 3) | (ln & 7)] =
            f2bf(fmaxf(acc[rt][ct][ri] + bv, 0.0f));
      }
    }
  }
  __syncthreads();

  // ---- GEMM2: Q = H@W2 + b2 ----
  gemm_frag(sm.F, ws + 65536, rh, cq, lane, acc);
  float bvb0 = b2[64 * cq + ln],      bvb1 = b2[64 * cq + 16 + ln];
  float bvb2 = b2[64 * cq + 32 + ln], bvb3 = b2[64 * cq + 48 + ln];
  __syncthreads();  // all H reads complete before overwriting F with Q
#pragma unroll
  for (int ct = 0; ct < 4; ++ct) {
    float bv = (ct == 0) ? bvb0 : (ct == 1) ? bvb1 : (ct == 2) ? bvb2 : bvb3;
    int ki2 = 2 * cq + (ct >> 1);
    int g2 = 2 * (ct & 1) + (ln >> 3);
#pragma unroll
    for (int rt = 0; rt < 2; ++rt) {
      int rtg = 2 * rh + rt;
#pragma unroll
      for (int ri = 0; ri < 4; ++ri) {
        int lane2 = g2 * 16 + 4 * g + ri;
        sm.F[(((ki2 * 4 + rtg) * 64 + lane2) << 3) | (ln & 7)] =
            f2bf(acc[rt][ct][ri] + bv);
      }
    }
  }
  __syncthreads();

  // ---- C^2 = nq + nr - 2 q.r : waves 0-3 dot tiles (MFMA), waves 4-7 norms ----
  f32x4 dacc = f32x4{0.f, 0.f, 0.f, 0.f};
  if (w < 4) {
    const int mt = w >> 1, nt = w & 1;  // q row-tile, r row-tile
    __builtin_amdgcn_s_setprio(1);
#pragma unroll
    for (int ki = 0; ki < 8; ++ki) {
      // A = q rows tile mt; B = r rows tile (2+nt) — A-frag of r IS B-frag of r^T
      short8 aq = *reinterpret_cast<const short8*>(
          &sm.F[(((ki * 4 + mt) * 64 + lane) << 3)]);
      short8 br = *reinterpret_cast<const short8*>(
          &sm.F[(((ki * 4 + 2 + nt) * 64 + lane) << 3)]);
      dacc = MFMA(aq, br, dacc);
    }
    __builtin_amdgcn_s_setprio(0);
  } else {
    const int t = w - 4;  // row-tile t: rows 16t .. 16t+15
    float s = 0.f;
#pragma unroll
    for (int ki = 0; ki < 8; ++ki) {
      short8 v = *reinterpret_cast<const short8*>(
          &sm.F[(((ki * 4 + t) * 64 + lane) << 3)]);
#pragma unroll
      for (int i = 0; i < 8; ++i) {
        float f = bf2f((u16)v[i]);
        s = fmaf(f, f, s);
      }
    }
    s += __shfl_xor(s, 16);  // reduce over k-groups g (same row, different k slice)
    s += __shfl_xor(s, 32);
    if (lane < 16) sm.nrm[t * 16 + lane] = s;
  }
  __syncthreads();

  if (w < 4) {
    const int mt = w >> 1, nt = w & 1;
    float* Cp = CO + (size_t)b * 1024;
#pragma unroll
    for (int ri = 0; ri < 4; ++ri) {
      int k = mt * 16 + 4 * g + ri;   // D layout: row = 4g+ri, col = ln
      int m = nt * 16 + ln;
      float sq = sm.nrm[k] + sm.nrm[32 + m] - 2.0f * dacc[ri];
      Cp[k * 32 + m] = sqrtf(fmaxf(sq, 0.0f));
    }
  }
}

// ---------------- kernel B: 1 wave = 1 problem, no barriers ----------------
__global__ __launch_bounds__(256, 4) void sinkhorn_mesh(
    const float* __restrict__ CO, float* __restrict__ simO,
    float* __restrict__ TO, float* __restrict__ costO, int Bn) {
  __shared__ float Wl[4][32 * 33];
  __shared__ float ABl[4][64];
  const int wv = threadIdx.x >> 6, lane = threadIdx.x & 63;
  const int p = blockIdx.x * 4 + wv;
  if (p >= Bn) return;
  const int h = lane >> 5, q = lane & 31;  // q = row k (row ops) / col (col ops)
  float* Wm = Wl[wv];
  float* LA = ABl[wv];
  float* LB = ABl[wv] + 32;
  const float* Cp = CO + (size_t)p * 1024;

  // lane holds row q cols [16h,16h+16) in lkr, col q rows [16h,16h+16) in lkc
  float lkr[16], lkc[16];
#pragma unroll
  for (int jj = 0; jj < 4; ++jj) {
    float4 v = *reinterpret_cast<const float4*>(Cp + q * 32 + h * 16 + jj * 4);
    int base = q * 33 + h * 16 + jj * 4;
    Wm[base + 0] = v.x; Wm[base + 1] = v.y; Wm[base + 2] = v.z; Wm[base + 3] = v.w;
    lkr[jj * 4 + 0] = -20.f * v.x; lkr[jj * 4 + 1] = -20.f * v.y;
    lkr[jj * 4 + 2] = -20.f * v.z; lkr[jj * 4 + 3] = -20.f * v.w;
  }
  LB[q] = 0.0f;
  __builtin_amdgcn_wave_barrier();
#pragma unroll
  for (int j = 0; j < 16; ++j) lkc[j] = -20.f * Wm[(h * 16 + j) * 33 + q];

  for (int it = 0; it < 15; ++it) {
    float v[16], mx, s;
#pragma unroll
    for (int j = 0; j < 16; ++j) v[j] = lkr[j] + LB[h * 16 + j];
    mx = v[0];
#pragma unroll
    for (int j = 1; j < 16; ++j) mx = fmaxf(mx, v[j]);
    mx = fmaxf(mx, __shfl_xor(mx, 32));
    s = 0.f;
#pragma unroll
    for (int j = 0; j < 16; ++j) s += __expf(v[j] - mx);
    s += __shfl_xor(s, 32);
    LA[q] = -(mx + __logf(s));  // both halves write identical value
    __builtin_amdgcn_wave_barrier();
#pragma unroll
    for (int j = 0; j < 16; ++j) v[j] = lkc[j] + LA[h * 16 + j];
    mx = v[0];
#pragma unroll
    for (int j = 1; j < 16; ++j) mx = fmaxf(mx, v[j]);
    mx = fmaxf(mx, __shfl_xor(mx, 32));
    s = 0.f;
#pragma unroll
    for (int j = 0; j < 16; ++j) s += __expf(v[j] - mx);
    s += __shfl_xor(s, 32);
    LB[q] = -(mx + __logf(s));
    __builtin_amdgcn_wave_barrier();
  }

  // T = exp(log_K + la + lb), row view
  float t[16];
  {
    float la = LA[q];
#pragma unroll
    for (int j = 0; j < 16; ++j) t[j] = __expf(lkr[j] + la + LB[h * 16 + j]);
  }

  // mesh: T=T^2; row-norm; col-norm (via LDS transpose; wave-sync only)
  for (int mi = 0; mi < 3; ++mi) {
    float s = 0.f;
#pragma unroll
    for (int j = 0; j < 16; ++j) { t[j] *= t[j]; s += t[j]; }
    s += __shfl_xor(s, 32);
    float inv = 1.0f / (s + 1e-8f);
#pragma unroll
    for (int j = 0; j < 16; ++j) Wm[q * 33 + h * 16 + j] = t[j] * inv;
    __builtin_amdgcn_wave_barrier();
#pragma unroll
    for (int j = 0; j < 16; ++j) t[j] = Wm[(h * 16 + j) * 33 + q];  // col view
    s = 0.f;
#pragma unroll
    for (int j = 0; j < 16; ++j) s += t[j];
    s += __shfl_xor(s, 32);
    inv = 1.0f / (s + 1e-8f);
#pragma unroll
    for (int j = 0; j < 16; ++j) Wm[(h * 16 + j) * 33 + q] = t[j] * inv;
    __builtin_amdgcn_wave_barrier();
#pragma unroll
    for (int j = 0; j < 16; ++j) t[j] = Wm[q * 33 + h * 16 + j];  // back to rows
  }

  // cost = sum(T*C); C = -lkr/20
  float pp = 0.f;
#pragma unroll
  for (int j = 0; j < 16; ++j) pp = fmaf(t[j], -0.05f * lkr[j], pp);
  pp += __shfl_xor(pp, 1); pp += __shfl_xor(pp, 2); pp += __shfl_xor(pp, 4);
  pp += __shfl_xor(pp, 8); pp += __shfl_xor(pp, 16); pp += __shfl_xor(pp, 32);
  if (lane == 0) {
    costO[p] = pp;
    simO[p] = 1.0f / (1.0f + __expf(pp));  // sigmoid(-cost)
  }
  // T out (coalesced float4 from row view)
#pragma unroll
  for (int jj = 0; jj < 4; ++jj) {
    float4 o;
    o.x = t[jj * 4 + 0]; o.y = t[jj * 4 + 1];
    o.z = t[jj * 4 + 2]; o.w = t[jj * 4 + 3];
    *reinterpret_cast<float4*>(TO + (size_t)p * 1024 + q * 32 + h * 16 + jj * 4) = o;
  }
}

extern "C" void kernel_launch(void* const* d_in, const int* in_sizes, int n_in,
                              void* d_out, int out_size, void* d_ws, size_t ws_size,
                              hipStream_t stream) {
  const float* slots_q = (const float*)d_in[0];
  const float* slots_r = (const float*)d_in[1];
  const float* W1 = (const float*)d_in[2];
  const float* b1 = (const float*)d_in[3];
  const float* W2 = (const float*)d_in[4];
  const float* b2 = (const float*)d_in[5];
  float* out = (float*)d_out;

  const int Bn = in_sizes[0] / 8192;  // 32*256 per batch element
  u16* ws = (u16*)d_ws;               // 256 KB W fragments

  prep_w<<<dim3(512), dim3(256), 0, stream>>>(W1, W2, ws);

  float* simO = out;
  float* TO = out + Bn;
  float* CO = TO + (size_t)Bn * 1024;
  float* costO = CO + (size_t)Bn * 1024;

  gemm_cdist<<<dim3(Bn), dim3(512), 0, stream>>>(slots_q, slots_r, b1, b2, ws, CO);
  sinkhorn_mesh<<<dim3((Bn + 3) / 4), dim3(256), 0, stream>>>(CO, simO, TO, costO, Bn);
}

// Round 11
// 287.201 us; speedup vs baseline: 1.3591x; 1.1403x over previous
//
#include <hip/hip_runtime.h>
#include <hip/hip_bf16.h>

// SinkhornOT, fully-fused single kernel for MI355X (gfx950).
// gemm_sink (1 block = 1 batch elem, 512 thr, 33KB LDS, 4 blocks/CU):
//   X=[q;r] (64x256) -> bf16 fragment-major LDS (single in-place buffer F)
//   -> H=relu(X@W1+b1) (MFMA, in-place) -> Q=H@W2+b2 (in-place)
//   -> C via MFMA: C^2 = nq + nr - 2 q.r (waves 0-3 dot tiles, waves 4-7 norms)
//   -> C to global + LDS Cm (F reused as float scratch)
//   -> wave-0 tail: 15 log-Sinkhorn iters + T + 3 mesh + cost/sim + T out
//      (verified kernel-B body; waves 1-7 exit early -> cross-block desync).
// GEMM is EXACT r7 shape (4 A-frags, 2 B-frags, acc[4][2]) — the only
// allocator-stable config found; r9/r10 variants spilled (WRITE 200-400MB).
// LESSONS: r5/r6 no HBM data in VGPRs across GEMM (spill); r8 VGPR count is
// compiler-chosen; r9/r10 unified VGPR+AGPR budget at (512,8) is 64 — the
// scheduler hoists independent loads, so "reg reuse" tricks don't hold.
// prep_w packs W1/W2 as bf16 MFMA B-fragments (k-map k_local = 8g+j, used
// consistently for A and B so the bijection cancels; HW-validated r1-r10).

typedef unsigned short u16;
typedef short short8 __attribute__((ext_vector_type(8)));
typedef float f32x4  __attribute__((ext_vector_type(4)));

#define MFMA(a, b, c) __builtin_amdgcn_mfma_f32_16x16x32_bf16((a), (b), (c), 0, 0, 0)

static __device__ __forceinline__ u16 f2bf(float f) {  // native RNE cvt (pairs fuse to v_cvt_pk_bf16_f32)
  __hip_bfloat16 h = __float2bfloat16(f);
  return __builtin_bit_cast(u16, h);
}
static __device__ __forceinline__ float bf2f(u16 h) {
  return __uint_as_float(((unsigned)h) << 16);
}

// ---------------- W fragment prep ----------------
// lane l = g*16 + (n&15) holds B[k = ki*32 + 8g + j][col = 16*ctg + (n&15)]
// ws u16 layout: mat*65536 + ((ki*16 + ctg)*64 + lane)*8 + j   (256 KB total)
__global__ __launch_bounds__(256) void prep_w(const float* __restrict__ W1,
                                              const float* __restrict__ W2,
                                              u16* __restrict__ ws) {
  int id = blockIdx.x * 256 + threadIdx.x;  // 0..131071
  int mat = id >> 16;
  int e = id & 65535;   // e = k*256 + n
  int k = e >> 8, n = e & 255;
  float wv = (mat ? W2 : W1)[e];
  int ki = k >> 5, kl = k & 31;
  int g = kl >> 3, j = kl & 7;
  int lane = g * 16 + (n & 15);
  int ctg = n >> 4;
  ws[mat * 65536 + ((((ki * 16 + ctg) * 64 + lane) << 3) | j)] = f2bf(wv);
}

// ---------------- fused kernel ----------------
struct __align__(16) SMemA {
  u16 F[16384];    // 32KB: X frags -> H frags -> Q frags -> (float) Cm|Wm
  float nrm[64];   // row norms of Q; later LA[0:32] | LB[32:64]
};

// 64x256 @ 256x256: A fragment-major [ki*4+rt][lane][8] (contiguous b128/lane),
// B fragments from global ws. Wave w owns output cols [32w, 32w+32).
// EXACT r7 shape — do not modify (allocator-stable at (512,8)).
static __device__ __forceinline__ void gemm_frag(const u16* __restrict__ Af,
                                                 const u16* __restrict__ wf,
                                                 int w, int lane, f32x4 acc[4][2]) {
#pragma unroll
  for (int rt = 0; rt < 4; ++rt) {
    acc[rt][0] = f32x4{0.f, 0.f, 0.f, 0.f};
    acc[rt][1] = f32x4{0.f, 0.f, 0.f, 0.f};
  }
  __builtin_amdgcn_s_setprio(1);
#pragma unroll
  for (int ki = 0; ki < 8; ++ki) {
    const u16* bp = wf + (((ki * 16 + 2 * w) * 64 + lane) << 3);
    short8 b0 = *reinterpret_cast<const short8*>(bp);        // 16B/lane, coalesced
    short8 b1 = *reinterpret_cast<const short8*>(bp + 512);  // ct=1 record
    short8 a[4];
#pragma unroll
    for (int rt = 0; rt < 4; ++rt)
      a[rt] = *reinterpret_cast<const short8*>(Af + (((ki * 4 + rt) * 64 + lane) << 3));
#pragma unroll
    for (int rt = 0; rt < 4; ++rt) {
      acc[rt][0] = MFMA(a[rt], b0, acc[rt][0]);
      acc[rt][1] = MFMA(a[rt], b1, acc[rt][1]);
    }
  }
  __builtin_amdgcn_s_setprio(0);
}

__global__ __launch_bounds__(512, 8) void gemm_sink(
    const float* __restrict__ slots_q, const float* __restrict__ slots_r,
    const float* __restrict__ b1, const float* __restrict__ b2,
    const u16* __restrict__ ws, float* __restrict__ simO,
    float* __restrict__ TO, float* __restrict__ CO,
    float* __restrict__ costO) {
  __shared__ SMemA sm;
  const int tid = threadIdx.x, b = blockIdx.x;
  const int w = tid >> 6, lane = tid & 63, g = lane >> 4, ln = lane & 15;

  // ---- stage X fragment-major: slot s = (ki*4+rt)*64 + g*16 + ln ----
  {
    const float* srcq = slots_q + (size_t)b * 8192;
    const float* srcr = slots_r + (size_t)b * 8192;
#pragma unroll
    for (int ii = 0; ii < 4; ++ii) {
      int s = tid + ii * 512;  // 0..2047
      int ki = s >> 8, rt = (s >> 6) & 3, sg = (s >> 4) & 3, sln = s & 15;
      int row = rt * 16 + sln;
      const float* src = (row < 32) ? (srcq + row * 256) : (srcr + (row - 32) * 256);
      int k0 = ki * 32 + sg * 8;
      float4 v0 = *reinterpret_cast<const float4*>(src + k0);
      float4 v1 = *reinterpret_cast<const float4*>(src + k0 + 4);
      short8 o;
      o[0] = (short)f2bf(v0.x); o[1] = (short)f2bf(v0.y);
      o[2] = (short)f2bf(v0.z); o[3] = (short)f2bf(v0.w);
      o[4] = (short)f2bf(v1.x); o[5] = (short)f2bf(v1.y);
      o[6] = (short)f2bf(v1.z); o[7] = (short)f2bf(v1.w);
      *reinterpret_cast<short8*>(&sm.F[s << 3]) = o;  // contiguous, conflict-free
    }
  }
  float bv1a = b1[32 * w + ln], bv1b = b1[32 * w + 16 + ln];
  float bv2a = b2[32 * w + ln], bv2b = b2[32 * w + 16 + ln];
  __syncthreads();

  f32x4 acc[4][2];
  // ---- GEMM1: H = relu(X@W1 + b1) ----
  gemm_frag(sm.F, ws, w, lane, acc);
  __syncthreads();  // all X reads complete before overwriting F with H
#pragma unroll
  for (int ct = 0; ct < 2; ++ct) {
    float bv = ct ? bv1b : bv1a;
#pragma unroll
    for (int rt = 0; rt < 4; ++rt)
#pragma unroll
      for (int ri = 0; ri < 4; ++ri) {
        // D layout: row = rt*16 + 4g + ri, col = 32w + 16ct + ln (verified r1)
        int lane2 = (2 * ct + (ln >> 3)) * 16 + 4 * g + ri;
        sm.F[(((w * 4 + rt) * 64 + lane2) << 3) | (ln & 7)] =
            f2bf(fmaxf(acc[rt][ct][ri] + bv, 0.0f));
      }
  }
  __syncthreads();

  // ---- GEMM2: Q = H@W2 + b2 ----
  gemm_frag(sm.F, ws + 65536, w, lane, acc);
  __syncthreads();  // all H reads complete before overwriting F with Q
#pragma unroll
  for (int ct = 0; ct < 2; ++ct) {
    float bv = ct ? bv2b : bv2a;
#pragma unroll
    for (int rt = 0; rt < 4; ++rt)
#pragma unroll
      for (int ri = 0; ri < 4; ++ri) {
        int lane2 = (2 * ct + (ln >> 3)) * 16 + 4 * g + ri;
        sm.F[(((w * 4 + rt) * 64 + lane2) << 3) | (ln & 7)] =
            f2bf(acc[rt][ct][ri] + bv);
      }
  }
  __syncthreads();

  // ---- C^2 = nq + nr - 2 q.r : waves 0-3 dot tiles (MFMA), waves 4-7 norms ----
  f32x4 dacc = f32x4{0.f, 0.f, 0.f, 0.f};
  if (w < 4) {
    const int mt = w >> 1, nt = w & 1;  // q row-tile, r row-tile
    __builtin_amdgcn_s_setprio(1);
#pragma unroll
    for (int ki = 0; ki < 8; ++ki) {
      // A = q rows tile mt; B = r rows tile (2+nt) — A-frag of r IS B-frag of r^T
      short8 aq = *reinterpret_cast<const short8*>(
          &sm.F[(((ki * 4 + mt) * 64 + lane) << 3)]);
      short8 br = *reinterpret_cast<const short8*>(
          &sm.F[(((ki * 4 + 2 + nt) * 64 + lane) << 3)]);
      dacc = MFMA(aq, br, dacc);
    }
    __builtin_amdgcn_s_setprio(0);
  } else {
    const int t = w - 4;  // row-tile t: rows 16t .. 16t+15
    float s = 0.f;
#pragma unroll
    for (int ki = 0; ki < 8; ++ki) {
      short8 v = *reinterpret_cast<const short8*>(
          &sm.F[(((ki * 4 + t) * 64 + lane) << 3)]);
#pragma unroll
      for (int i = 0; i < 8; ++i) {
        float f = bf2f((u16)v[i]);
        s = fmaf(f, f, s);
      }
    }
    s += __shfl_xor(s, 16);  // reduce over k-groups g (same row, different k slice)
    s += __shfl_xor(s, 32);
    if (lane < 16) sm.nrm[t * 16 + lane] = s;
  }
  __syncthreads();  // nrm ready; all F reads done -> F reusable as float scratch

  float* Cm = reinterpret_cast<float*>(sm.F);        // [32*33]
  float* Wm = Cm + 1056;                             // [32*33]
  if (w < 4) {
    const int mt = w >> 1, nt = w & 1;
    float* Cp = CO + (size_t)b * 1024;
#pragma unroll
    for (int ri = 0; ri < 4; ++ri) {
      int k = mt * 16 + 4 * g + ri;   // D layout: row = 4g+ri, col = ln
      int m = nt * 16 + ln;
      float sq = sm.nrm[k] + sm.nrm[32 + m] - 2.0f * dacc[ri];
      float c = sqrtf(fmaxf(sq, 0.0f));
      Cp[k * 32 + m] = c;
      Cm[k * 33 + m] = c;
    }
  }
  __syncthreads();  // Cm published; nrm dead (becomes LA|LB)
  if (w != 0) return;  // waves 1-7 done; wave 0 runs sinkhorn+mesh tail

  // ---- wave-0 tail (verified kernel-B body; LDS-sourced C) ----
  const int h = lane >> 5, q = lane & 31;
  float* LA = sm.nrm;        // [32]
  float* LB = sm.nrm + 32;   // [32]
  float lkr[16];             // log_K row view = -C/EPS
#pragma unroll
  for (int j = 0; j < 16; ++j) lkr[j] = -20.f * Cm[q * 33 + h * 16 + j];
  if (lane < 32) LB[lane] = 0.0f;
  __builtin_amdgcn_wave_barrier();

  for (int it = 0; it < 15; ++it) {
    float v[16], mx, s;
#pragma unroll
    for (int j = 0; j < 16; ++j) v[j] = lkr[j] + LB[h * 16 + j];
    mx = v[0];
#pragma unroll
    for (int j = 1; j < 16; ++j) mx = fmaxf(mx, v[j]);
    mx = fmaxf(mx, __shfl_xor(mx, 32));
    s = 0.f;
#pragma unroll
    for (int j = 0; j < 16; ++j) s += __expf(v[j] - mx);
    s += __shfl_xor(s, 32);
    LA[q] = -(mx + __logf(s));  // both halves write identical value
    __builtin_amdgcn_wave_barrier();
    // col pass: lkc re-read from Cm (keeps tail live set ~44 VGPR)
#pragma unroll
    for (int j = 0; j < 16; ++j)
      v[j] = fmaf(-20.f, Cm[(h * 16 + j) * 33 + q], LA[h * 16 + j]);
    mx = v[0];
#pragma unroll
    for (int j = 1; j < 16; ++j) mx = fmaxf(mx, v[j]);
    mx = fmaxf(mx, __shfl_xor(mx, 32));
    s = 0.f;
#pragma unroll
    for (int j = 0; j < 16; ++j) s += __expf(v[j] - mx);
    s += __shfl_xor(s, 32);
    LB[q] = -(mx + __logf(s));
    __builtin_amdgcn_wave_barrier();
  }

  // T = exp(log_K + la + lb), row view
  float t[16];
  {
    float la = LA[q];
#pragma unroll
    for (int j = 0; j < 16; ++j) t[j] = __expf(lkr[j] + la + LB[h * 16 + j]);
  }

  // mesh: T=T^2; row-norm; col-norm (via LDS transpose; wave-sync only)
  for (int mi = 0; mi < 3; ++mi) {
    float s = 0.f;
#pragma unroll
    for (int j = 0; j < 16; ++j) { t[j] *= t[j]; s += t[j]; }
    s += __shfl_xor(s, 32);
    float inv = 1.0f / (s + 1e-8f);
#pragma unroll
    for (int j = 0; j < 16; ++j) Wm[q * 33 + h * 16 + j] = t[j] * inv;
    __builtin_amdgcn_wave_barrier();
#pragma unroll
    for (int j = 0; j < 16; ++j) t[j] = Wm[(h * 16 + j) * 33 + q];  // col view
    s = 0.f;
#pragma unroll
    for (int j = 0; j < 16; ++j) s += t[j];
    s += __shfl_xor(s, 32);
    inv = 1.0f / (s + 1e-8f);
#pragma unroll
    for (int j = 0; j < 16; ++j) Wm[(h * 16 + j) * 33 + q] = t[j] * inv;
    __builtin_amdgcn_wave_barrier();
#pragma unroll
    for (int j = 0; j < 16; ++j) t[j] = Wm[q * 33 + h * 16 + j];  // back to rows
  }

  // cost = sum(T*C); C = -lkr/20
  float pp = 0.f;
#pragma unroll
  for (int j = 0; j < 16; ++j) pp = fmaf(t[j], -0.05f * lkr[j], pp);
  pp += __shfl_xor(pp, 1); pp += __shfl_xor(pp, 2); pp += __shfl_xor(pp, 4);
  pp += __shfl_xor(pp, 8); pp += __shfl_xor(pp, 16); pp += __shfl_xor(pp, 32);
  if (lane == 0) {
    costO[b] = pp;
    simO[b] = 1.0f / (1.0f + __expf(pp));  // sigmoid(-cost)
  }
  // T out (coalesced float4 from row view)
#pragma unroll
  for (int jj = 0; jj < 4; ++jj) {
    float4 o;
    o.x = t[jj * 4 + 0]; o.y = t[jj * 4 + 1];
    o.z = t[jj * 4 + 2]; o.w = t[jj * 4 + 3];
    *reinterpret_cast<float4*>(TO + (size_t)b * 1024 + q * 32 + h * 16 + jj * 4) = o;
  }
}

extern "C" void kernel_launch(void* const* d_in, const int* in_sizes, int n_in,
                              void* d_out, int out_size, void* d_ws, size_t ws_size,
                              hipStream_t stream) {
  const float* slots_q = (const float*)d_in[0];
  const float* slots_r = (const float*)d_in[1];
  const float* W1 = (const float*)d_in[2];
  const float* b1 = (const float*)d_in[3];
  const float* W2 = (const float*)d_in[4];
  const float* b2 = (const float*)d_in[5];
  float* out = (float*)d_out;

  const int Bn = in_sizes[0] / 8192;  // 32*256 per batch element
  u16* ws = (u16*)d_ws;               // 256 KB W fragments

  prep_w<<<dim3(512), dim3(256), 0, stream>>>(W1, W2, ws);

  float* simO = out;
  float* TO = out + Bn;
  float* CO = TO + (size_t)Bn * 1024;
  float* costO = CO + (size_t)Bn * 1024;

  gemm_sink<<<dim3(Bn), dim3(512), 0, stream>>>(slots_q, slots_r, b1, b2, ws,
                                                simO, TO, CO, costO);
}

// Round 13
// 263.766 us; speedup vs baseline: 1.4798x; 1.0888x over previous
//
#include <hip/hip_runtime.h>
#include <hip/hip_bf16.h>

// SinkhornOT, split-kernel version for MI355X (gfx950). r13 = exact r7 (best:
// 227us A + 27us B) + nontemporal hints (slots loads in A, T stores in B),
// with ext_vector types for the NT builtins (HIP_vector_type float4 rejected).
// Kernel A (gemm_cdist, 1 block = 1 batch elem, 512 thr, 33KB LDS, 6 barriers,
//           4 blocks/CU):
//   X=[q;r] (64x256) -> bf16 fragment-major LDS (single in-place buffer)
//   -> H=relu(X@W1+b1) (MFMA, in-place) -> Q=H@W2+b2 (in-place)
//   -> C via MFMA: C^2 = nq + nr - 2 q.r  (waves 0-3 dot tiles, waves 4-7 norms)
// Kernel B (sinkhorn_mesh, 1 wave = 1 problem, no barriers, wave-sync LDS):
//   15 log-domain Sinkhorn iters + T + 3 mesh iters + cost/sim + T out.
// LESSON LOG: r5/r6 - no HBM data in VGPRs across a GEMM phase (scratch spill,
//   WRITE 0.6-1GB). r8 - VGPR count is compiler-chosen; don't trade occupancy
//   for unused budget. r9/r10 - unified VGPR+AGPR budget at (512,8) is 64;
//   scheduler hoists independent loads so reg-reuse tricks spill anyway; the
//   r7 GEMM shape (4 A-frags, 2 B-frags, acc[4][2]) is the only stable point.
// r11 - fused sinkhorn tail = 1 wave holding block resources for ~12K serial
//   cycles; split kernel B amortizes it 16 waves/CU. Never fuse long serial
//   tails into resource-holding blocks. r12 - NT builtins need ext_vector types.
// prep_w packs W1/W2 as bf16 MFMA B-fragments (k-map k_local = 8g+j, used
// consistently for A and B so the bijection cancels; HW-validated r1-r11).

typedef unsigned short u16;
typedef short short8 __attribute__((ext_vector_type(8)));
typedef float f32x4  __attribute__((ext_vector_type(4)));

#define MFMA(a, b, c) __builtin_amdgcn_mfma_f32_16x16x32_bf16((a), (b), (c), 0, 0, 0)

static __device__ __forceinline__ u16 f2bf(float f) {  // native RNE cvt (pairs fuse to v_cvt_pk_bf16_f32)
  __hip_bfloat16 h = __float2bfloat16(f);
  return __builtin_bit_cast(u16, h);
}
static __device__ __forceinline__ float bf2f(u16 h) {
  return __uint_as_float(((unsigned)h) << 16);
}

// ---------------- W fragment prep ----------------
// lane l = g*16 + (n&15) holds B[k = ki*32 + 8g + j][col = 16*ctg + (n&15)]
// ws u16 layout: mat*65536 + ((ki*16 + ctg)*64 + lane)*8 + j   (256 KB total)
__global__ __launch_bounds__(256) void prep_w(const float* __restrict__ W1,
                                              const float* __restrict__ W2,
                                              u16* __restrict__ ws) {
  int id = blockIdx.x * 256 + threadIdx.x;  // 0..131071
  int mat = id >> 16;
  int e = id & 65535;   // e = k*256 + n
  int k = e >> 8, n = e & 255;
  float wv = (mat ? W2 : W1)[e];
  int ki = k >> 5, kl = k & 31;
  int g = kl >> 3, j = kl & 7;
  int lane = g * 16 + (n & 15);
  int ctg = n >> 4;
  ws[mat * 65536 + ((((ki * 16 + ctg) * 64 + lane) << 3) | j)] = f2bf(wv);
}

// ---------------- kernel A ----------------
struct __align__(16) SMemA {
  u16 F[16384];    // 32KB single buffer: X frags -> H frags -> Q frags (in place)
  float nrm[64];   // row norms of Q (0-31 q, 32-63 r)
};

// 64x256 @ 256x256: A fragment-major [ki*4+rt][lane][8] (contiguous b128/lane),
// B fragments from global ws. Wave w owns output cols [32w, 32w+32).
// EXACT r7 shape — allocator-stable at (512,8); do not modify.
static __device__ __forceinline__ void gemm_frag(const u16* __restrict__ Af,
                                                 const u16* __restrict__ wf,
                                                 int w, int lane, f32x4 acc[4][2]) {
#pragma unroll
  for (int rt = 0; rt < 4; ++rt) {
    acc[rt][0] = f32x4{0.f, 0.f, 0.f, 0.f};
    acc[rt][1] = f32x4{0.f, 0.f, 0.f, 0.f};
  }
  __builtin_amdgcn_s_setprio(1);
#pragma unroll
  for (int ki = 0; ki < 8; ++ki) {
    const u16* bp = wf + (((ki * 16 + 2 * w) * 64 + lane) << 3);
    short8 b0 = *reinterpret_cast<const short8*>(bp);        // 16B/lane, coalesced
    short8 b1 = *reinterpret_cast<const short8*>(bp + 512);  // ct=1 record
    short8 a[4];
#pragma unroll
    for (int rt = 0; rt < 4; ++rt)
      a[rt] = *reinterpret_cast<const short8*>(Af + (((ki * 4 + rt) * 64 + lane) << 3));
#pragma unroll
    for (int rt = 0; rt < 4; ++rt) {
      acc[rt][0] = MFMA(a[rt], b0, acc[rt][0]);
      acc[rt][1] = MFMA(a[rt], b1, acc[rt][1]);
    }
  }
  __builtin_amdgcn_s_setprio(0);
}

__global__ __launch_bounds__(512, 8) void gemm_cdist(
    const float* __restrict__ slots_q, const float* __restrict__ slots_r,
    const float* __restrict__ b1, const float* __restrict__ b2,
    const u16* __restrict__ ws, float* __restrict__ CO) {
  __shared__ SMemA sm;
  const int tid = threadIdx.x, b = blockIdx.x;
  const int w = tid >> 6, lane = tid & 63, g = lane >> 4, ln = lane & 15;

  // ---- stage X fragment-major: slot s = (ki*4+rt)*64 + g*16 + ln ----
  {
    const float* srcq = slots_q + (size_t)b * 8192;
    const float* srcr = slots_r + (size_t)b * 8192;
#pragma unroll
    for (int ii = 0; ii < 4; ++ii) {
      int s = tid + ii * 512;  // 0..2047
      int ki = s >> 8, rt = (s >> 6) & 3, sg = (s >> 4) & 3, sln = s & 15;
      int row = rt * 16 + sln;
      const float* src = (row < 32) ? (srcq + row * 256) : (srcr + (row - 32) * 256);
      int k0 = ki * 32 + sg * 8;
      // streamed-once input: nontemporal keeps ws/C lines resident in L2
      f32x4 v0 = __builtin_nontemporal_load(
          reinterpret_cast<const f32x4*>(src + k0));
      f32x4 v1 = __builtin_nontemporal_load(
          reinterpret_cast<const f32x4*>(src + k0 + 4));
      short8 o;
      o[0] = (short)f2bf(v0[0]); o[1] = (short)f2bf(v0[1]);
      o[2] = (short)f2bf(v0[2]); o[3] = (short)f2bf(v0[3]);
      o[4] = (short)f2bf(v1[0]); o[5] = (short)f2bf(v1[1]);
      o[6] = (short)f2bf(v1[2]); o[7] = (short)f2bf(v1[3]);
      *reinterpret_cast<short8*>(&sm.F[s << 3]) = o;  // contiguous, conflict-free
    }
  }
  float bv1a = b1[32 * w + ln], bv1b = b1[32 * w + 16 + ln];
  float bv2a = b2[32 * w + ln], bv2b = b2[32 * w + 16 + ln];
  __syncthreads();

  f32x4 acc[4][2];
  // ---- GEMM1: H = relu(X@W1 + b1) ----
  gemm_frag(sm.F, ws, w, lane, acc);
  __syncthreads();  // all X reads complete before overwriting F with H
#pragma unroll
  for (int ct = 0; ct < 2; ++ct) {
    float bv = ct ? bv1b : bv1a;
#pragma unroll
    for (int rt = 0; rt < 4; ++rt)
#pragma unroll
      for (int ri = 0; ri < 4; ++ri) {
        // D layout: row = rt*16 + 4g + ri, col = 32w + 16ct + ln (verified r1)
        int lane2 = (2 * ct + (ln >> 3)) * 16 + 4 * g + ri;
        sm.F[(((w * 4 + rt) * 64 + lane2) << 3) | (ln & 7)] =
            f2bf(fmaxf(acc[rt][ct][ri] + bv, 0.0f));
      }
  }
  __syncthreads();

  // ---- GEMM2: Q = H@W2 + b2 ----
  gemm_frag(sm.F, ws + 65536, w, lane, acc);
  __syncthreads();  // all H reads complete before overwriting F with Q
#pragma unroll
  for (int ct = 0; ct < 2; ++ct) {
    float bv = ct ? bv2b : bv2a;
#pragma unroll
    for (int rt = 0; rt < 4; ++rt)
#pragma unroll
      for (int ri = 0; ri < 4; ++ri) {
        int lane2 = (2 * ct + (ln >> 3)) * 16 + 4 * g + ri;
        sm.F[(((w * 4 + rt) * 64 + lane2) << 3) | (ln & 7)] =
            f2bf(acc[rt][ct][ri] + bv);
      }
  }
  __syncthreads();

  // ---- C^2 = nq + nr - 2 q.r : waves 0-3 dot tiles (MFMA), waves 4-7 norms ----
  f32x4 dacc = f32x4{0.f, 0.f, 0.f, 0.f};
  if (w < 4) {
    const int mt = w >> 1, nt = w & 1;  // q row-tile, r row-tile
    __builtin_amdgcn_s_setprio(1);
#pragma unroll
    for (int ki = 0; ki < 8; ++ki) {
      // A = q rows tile mt; B = r rows tile (2+nt) — A-frag of r IS B-frag of r^T
      short8 aq = *reinterpret_cast<const short8*>(
          &sm.F[(((ki * 4 + mt) * 64 + lane) << 3)]);
      short8 br = *reinterpret_cast<const short8*>(
          &sm.F[(((ki * 4 + 2 + nt) * 64 + lane) << 3)]);
      dacc = MFMA(aq, br, dacc);
    }
    __builtin_amdgcn_s_setprio(0);
  } else {
    const int t = w - 4;  // row-tile t: rows 16t .. 16t+15
    float s = 0.f;
#pragma unroll
    for (int ki = 0; ki < 8; ++ki) {
      short8 v = *reinterpret_cast<const short8*>(
          &sm.F[(((ki * 4 + t) * 64 + lane) << 3)]);
#pragma unroll
      for (int i = 0; i < 8; ++i) {
        float f = bf2f((u16)v[i]);
        s = fmaf(f, f, s);
      }
    }
    s += __shfl_xor(s, 16);  // reduce over k-groups g (same row, different k slice)
    s += __shfl_xor(s, 32);
    if (lane < 16) sm.nrm[t * 16 + lane] = s;
  }
  __syncthreads();

  if (w < 4) {
    const int mt = w >> 1, nt = w & 1;
    float* Cp = CO + (size_t)b * 1024;
#pragma unroll
    for (int ri = 0; ri < 4; ++ri) {
      int k = mt * 16 + 4 * g + ri;   // D layout: row = 4g+ri, col = ln
      int m = nt * 16 + ln;
      float sq = sm.nrm[k] + sm.nrm[32 + m] - 2.0f * dacc[ri];
      Cp[k * 32 + m] = sqrtf(fmaxf(sq, 0.0f));
    }
  }
}

// ---------------- kernel B: 1 wave = 1 problem, no barriers ----------------
__global__ __launch_bounds__(256, 4) void sinkhorn_mesh(
    const float* __restrict__ CO, float* __restrict__ simO,
    float* __restrict__ TO, float* __restrict__ costO, int Bn) {
  __shared__ float Wl[4][32 * 33];
  __shared__ float ABl[4][64];
  const int wv = threadIdx.x >> 6, lane = threadIdx.x & 63;
  const int p = blockIdx.x * 4 + wv;
  if (p >= Bn) return;
  const int h = lane >> 5, q = lane & 31;  // q = row k (row ops) / col (col ops)
  float* Wm = Wl[wv];
  float* LA = ABl[wv];
  float* LB = ABl[wv] + 32;
  const float* Cp = CO + (size_t)p * 1024;

  // lane holds row q cols [16h,16h+16) in lkr, col q rows [16h,16h+16) in lkc
  float lkr[16], lkc[16];
#pragma unroll
  for (int jj = 0; jj < 4; ++jj) {
    f32x4 v = *reinterpret_cast<const f32x4*>(Cp + q * 32 + h * 16 + jj * 4);
    int base = q * 33 + h * 16 + jj * 4;
    Wm[base + 0] = v[0]; Wm[base + 1] = v[1]; Wm[base + 2] = v[2]; Wm[base + 3] = v[3];
    lkr[jj * 4 + 0] = -20.f * v[0]; lkr[jj * 4 + 1] = -20.f * v[1];
    lkr[jj * 4 + 2] = -20.f * v[2]; lkr[jj * 4 + 3] = -20.f * v[3];
  }
  LB[q] = 0.0f;
  __builtin_amdgcn_wave_barrier();
#pragma unroll
  for (int j = 0; j < 16; ++j) lkc[j] = -20.f * Wm[(h * 16 + j) * 33 + q];

  for (int it = 0; it < 15; ++it) {
    float v[16], mx, s;
#pragma unroll
    for (int j = 0; j < 16; ++j) v[j] = lkr[j] + LB[h * 16 + j];
    mx = v[0];
#pragma unroll
    for (int j = 1; j < 16; ++j) mx = fmaxf(mx, v[j]);
    mx = fmaxf(mx, __shfl_xor(mx, 32));
    s = 0.f;
#pragma unroll
    for (int j = 0; j < 16; ++j) s += __expf(v[j] - mx);
    s += __shfl_xor(s, 32);
    LA[q] = -(mx + __logf(s));  // both halves write identical value
    __builtin_amdgcn_wave_barrier();
#pragma unroll
    for (int j = 0; j < 16; ++j) v[j] = lkc[j] + LA[h * 16 + j];
    mx = v[0];
#pragma unroll
    for (int j = 1; j < 16; ++j) mx = fmaxf(mx, v[j]);
    mx = fmaxf(mx, __shfl_xor(mx, 32));
    s = 0.f;
#pragma unroll
    for (int j = 0; j < 16; ++j) s += __expf(v[j] - mx);
    s += __shfl_xor(s, 32);
    LB[q] = -(mx + __logf(s));
    __builtin_amdgcn_wave_barrier();
  }

  // T = exp(log_K + la + lb), row view
  float t[16];
  {
    float la = LA[q];
#pragma unroll
    for (int j = 0; j < 16; ++j) t[j] = __expf(lkr[j] + la + LB[h * 16 + j]);
  }

  // mesh: T=T^2; row-norm; col-norm (via LDS transpose; wave-sync only)
  for (int mi = 0; mi < 3; ++mi) {
    float s = 0.f;
#pragma unroll
    for (int j = 0; j < 16; ++j) { t[j] *= t[j]; s += t[j]; }
    s += __shfl_xor(s, 32);
    float inv = 1.0f / (s + 1e-8f);
#pragma unroll
    for (int j = 0; j < 16; ++j) Wm[q * 33 + h * 16 + j] = t[j] * inv;
    __builtin_amdgcn_wave_barrier();
#pragma unroll
    for (int j = 0; j < 16; ++j) t[j] = Wm[(h * 16 + j) * 33 + q];  // col view
    s = 0.f;
#pragma unroll
    for (int j = 0; j < 16; ++j) s += t[j];
    s += __shfl_xor(s, 32);
    inv = 1.0f / (s + 1e-8f);
#pragma unroll
    for (int j = 0; j < 16; ++j) Wm[(h * 16 + j) * 33 + q] = t[j] * inv;
    __builtin_amdgcn_wave_barrier();
#pragma unroll
    for (int j = 0; j < 16; ++j) t[j] = Wm[q * 33 + h * 16 + j];  // back to rows
  }

  // cost = sum(T*C); C = -lkr/20
  float pp = 0.f;
#pragma unroll
  for (int j = 0; j < 16; ++j) pp = fmaf(t[j], -0.05f * lkr[j], pp);
  pp += __shfl_xor(pp, 1); pp += __shfl_xor(pp, 2); pp += __shfl_xor(pp, 4);
  pp += __shfl_xor(pp, 8); pp += __shfl_xor(pp, 16); pp += __shfl_xor(pp, 32);
  if (lane == 0) {
    costO[p] = pp;
    simO[p] = 1.0f / (1.0f + __expf(pp));  // sigmoid(-cost)
  }
  // T out (coalesced, written once never re-read -> nontemporal)
#pragma unroll
  for (int jj = 0; jj < 4; ++jj) {
    f32x4 o;
    o[0] = t[jj * 4 + 0]; o[1] = t[jj * 4 + 1];
    o[2] = t[jj * 4 + 2]; o[3] = t[jj * 4 + 3];
    __builtin_nontemporal_store(
        o, reinterpret_cast<f32x4*>(TO + (size_t)p * 1024 + q * 32 + h * 16 + jj * 4));
  }
}

extern "C" void kernel_launch(void* const* d_in, const int* in_sizes, int n_in,
                              void* d_out, int out_size, void* d_ws, size_t ws_size,
                              hipStream_t stream) {
  const float* slots_q = (const float*)d_in[0];
  const float* slots_r = (const float*)d_in[1];
  const float* W1 = (const float*)d_in[2];
  const float* b1 = (const float*)d_in[3];
  const float* W2 = (const float*)d_in[4];
  const float* b2 = (const float*)d_in[5];
  float* out = (float*)d_out;

  const int Bn = in_sizes[0] / 8192;  // 32*256 per batch element
  u16* ws = (u16*)d_ws;               // 256 KB W fragments

  prep_w<<<dim3(512), dim3(256), 0, stream>>>(W1, W2, ws);

  float* simO = out;
  float* TO = out + Bn;
  float* CO = TO + (size_t)Bn * 1024;
  float* costO = CO + (size_t)Bn * 1024;

  gemm_cdist<<<dim3(Bn), dim3(512), 0, stream>>>(slots_q, slots_r, b1, b2, ws, CO);
  sinkhorn_mesh<<<dim3((Bn + 3) / 4), dim3(256), 0, stream>>>(CO, simO, TO, costO, Bn);
}

// Round 14
// 263.056 us; speedup vs baseline: 1.4838x; 1.0027x over previous
//
#include <hip/hip_runtime.h>
#include <hip/hip_bf16.h>

// SinkhornOT, split-kernel version for MI355X (gfx950). r14: 2 problems per
// block at __launch_bounds__(512,4) (128-VGPR budget; LDS 66KB caps occupancy
// at 2 blocks/CU regardless, so the bigger register budget is free).
// Kernel A (gemm_cdist2, 1 block = 2 batch elems, 512 thr, 66KB LDS,
//           3 barriers/problem):
//   X=[q0;r0;q1;r1] (128x256) -> bf16 fragment-major LDS (in-place buffer)
//   -> H=relu(X@W1+b1) -> Q=H@W2+b2 (wave tile 64r x 64c, acc[4][4])
//   -> cdist: all 8 waves norms (row-tile w) + one dot tile each (w=P*4+2mt+nt)
// Benefits vs r7/r13: W L2 traffic per problem halved, barriers/problem
// halved, 2x MFMA ILP per wave. Cost: TLP 8->4 waves/SIMD.
// Kernel B (sinkhorn_mesh) unchanged (verified r2-r13).
// LESSON LOG: r5/r6 no HBM data in VGPRs across GEMM (spill). r8 VGPR count is
// compiler-chosen. r9/r10 at (512,8) the unified 64-VGPR budget spills for any
// tile >acc[4][2]; here budget=128, peak live ~100. r11 never fuse long serial
// tails into resource-holding blocks. r12 NT builtins need ext_vector types.
// prep_w packs W1/W2 as bf16 MFMA B-fragments (k-map k_local=8g+j, consistent
// on A and B sides so the bijection cancels; HW-validated r1-r13).

typedef unsigned short u16;
typedef short short8 __attribute__((ext_vector_type(8)));
typedef float f32x4  __attribute__((ext_vector_type(4)));

#define MFMA(a, b, c) __builtin_amdgcn_mfma_f32_16x16x32_bf16((a), (b), (c), 0, 0, 0)

static __device__ __forceinline__ u16 f2bf(float f) {  // native RNE cvt
  __hip_bfloat16 h = __float2bfloat16(f);
  return __builtin_bit_cast(u16, h);
}
static __device__ __forceinline__ float bf2f(u16 h) {
  return __uint_as_float(((unsigned)h) << 16);
}

// ---------------- W fragment prep ----------------
// lane l = g*16 + (n&15) holds B[k = ki*32 + 8g + j][col = 16*ctg + (n&15)]
// ws u16 layout: mat*65536 + ((ki*16 + ctg)*64 + lane)*8 + j   (256 KB total)
__global__ __launch_bounds__(256) void prep_w(const float* __restrict__ W1,
                                              const float* __restrict__ W2,
                                              u16* __restrict__ ws) {
  int id = blockIdx.x * 256 + threadIdx.x;  // 0..131071
  int mat = id >> 16;
  int e = id & 65535;   // e = k*256 + n
  int k = e >> 8, n = e & 255;
  float wv = (mat ? W2 : W1)[e];
  int ki = k >> 5, kl = k & 31;
  int g = kl >> 3, j = kl & 7;
  int lane = g * 16 + (n & 15);
  int ctg = n >> 4;
  ws[mat * 65536 + ((((ki * 16 + ctg) * 64 + lane) << 3) | j)] = f2bf(wv);
}

// ---------------- kernel A (2 problems / block) ----------------
struct __align__(16) SMemA2 {
  u16 F[32768];     // 64KB: X2 frags -> H2 frags -> Q2 frags (in place)
  float nrm[128];   // row norms (2 problems x [q 0-31 | r 32-63])
};

// 128x256 @ 256x256, wave tile 64 rows x 64 cols:
//   rh = w&1 (row-tiles 4rh..4rh+3), cq = w>>1 (cols 64cq, B recs 4cq..4cq+3).
// B loaded as two reg-reused pairs; peak live ~ acc64 + a16 + b8 + addr < 128.
static __device__ __forceinline__ void gemm_frag2(const u16* __restrict__ Af,
                                                  const u16* __restrict__ wf,
                                                  int rh, int cq, int lane,
                                                  f32x4 acc[4][4]) {
#pragma unroll
  for (int rt = 0; rt < 4; ++rt)
#pragma unroll
    for (int ct = 0; ct < 4; ++ct) acc[rt][ct] = f32x4{0.f, 0.f, 0.f, 0.f};
  __builtin_amdgcn_s_setprio(1);
#pragma unroll
  for (int ki = 0; ki < 8; ++ki) {
    short8 a[4];
#pragma unroll
    for (int rt = 0; rt < 4; ++rt)
      a[rt] = *reinterpret_cast<const short8*>(
          Af + (((ki * 8 + 4 * rh + rt) * 64 + lane) << 3));
    const u16* bp = wf + (((ki * 16 + 4 * cq) * 64 + lane) << 3);
    {
      short8 bx = *reinterpret_cast<const short8*>(bp);
      short8 by = *reinterpret_cast<const short8*>(bp + 512);
#pragma unroll
      for (int rt = 0; rt < 4; ++rt) {
        acc[rt][0] = MFMA(a[rt], bx, acc[rt][0]);
        acc[rt][1] = MFMA(a[rt], by, acc[rt][1]);
      }
    }
    {
      short8 bx = *reinterpret_cast<const short8*>(bp + 1024);
      short8 by = *reinterpret_cast<const short8*>(bp + 1536);
#pragma unroll
      for (int rt = 0; rt < 4; ++rt) {
        acc[rt][2] = MFMA(a[rt], bx, acc[rt][2]);
        acc[rt][3] = MFMA(a[rt], by, acc[rt][3]);
      }
    }
  }
  __builtin_amdgcn_s_setprio(0);
}

__global__ __launch_bounds__(512, 4) void gemm_cdist2(
    const float* __restrict__ slots_q, const float* __restrict__ slots_r,
    const float* __restrict__ b1, const float* __restrict__ b2,
    const u16* __restrict__ ws, float* __restrict__ CO, int Bn) {
  __shared__ SMemA2 sm;
  const int tid = threadIdx.x;
  const int w = tid >> 6, lane = tid & 63, g = lane >> 4, ln = lane & 15;
  const int rh = w & 1, cq = w >> 1;
  const int pb = blockIdx.x * 2;

  // ---- stage X2 fragment-major: slot s = (ki*8+rt)*64 + g*16 + sln ----
  {
#pragma unroll
    for (int ii = 0; ii < 8; ++ii) {
      int s = tid + ii * 512;  // 0..4095
      int sln = s & 15, sg = (s >> 4) & 3, rt = (s >> 6) & 7, ki = s >> 9;
      int row = rt * 16 + sln;            // 0..127
      int P = row >> 6, rl = row & 63;    // problem, local row
      int pidx = (pb + P < Bn) ? (pb + P) : (Bn - 1);
      size_t base = (size_t)pidx * 8192;
      const float* src = (rl < 32) ? (slots_q + base + rl * 256)
                                   : (slots_r + base + (rl - 32) * 256);
      int k0 = ki * 32 + sg * 8;
      f32x4 v0 = __builtin_nontemporal_load(reinterpret_cast<const f32x4*>(src + k0));
      f32x4 v1 = __builtin_nontemporal_load(reinterpret_cast<const f32x4*>(src + k0 + 4));
      short8 o;
      o[0] = (short)f2bf(v0[0]); o[1] = (short)f2bf(v0[1]);
      o[2] = (short)f2bf(v0[2]); o[3] = (short)f2bf(v0[3]);
      o[4] = (short)f2bf(v1[0]); o[5] = (short)f2bf(v1[1]);
      o[6] = (short)f2bf(v1[2]); o[7] = (short)f2bf(v1[3]);
      *reinterpret_cast<short8*>(&sm.F[s << 3]) = o;
    }
  }
  __syncthreads();

  f32x4 acc[4][4];
  // ---- GEMM1: H2 = relu(X2@W1 + b1) ----
  gemm_frag2(sm.F, ws, rh, cq, lane, acc);
  float bv0 = b1[64 * cq + ln],      bv1 = b1[64 * cq + 16 + ln];
  float bv2 = b1[64 * cq + 32 + ln], bv3 = b1[64 * cq + 48 + ln];
  __syncthreads();  // all X reads complete before overwriting F with H
#pragma unroll
  for (int ct = 0; ct < 4; ++ct) {
    float bv = (ct == 0) ? bv0 : (ct == 1) ? bv1 : (ct == 2) ? bv2 : bv3;
    int ki2 = 2 * cq + (ct >> 1);          // (64cq+16ct+ln) >> 5
    int g2 = 2 * (ct & 1) + (ln >> 3);
#pragma unroll
    for (int rt = 0; rt < 4; ++rt) {
      int rtg = 4 * rh + rt;               // global row-tile
#pragma unroll
      for (int ri = 0; ri < 4; ++ri) {
        int lane2 = g2 * 16 + 4 * g + ri;  // D: row = 16rtg+4g+ri (verified r1)
        sm.F[(((ki2 * 8 + rtg) * 64 + lane2) << 3) | (ln & 7)] =
            f2bf(fmaxf(acc[rt][ct][ri] + bv, 0.0f));
      }
    }
  }
  __syncthreads();

  // ---- GEMM2: Q2 = H2@W2 + b2 ----
  gemm_frag2(sm.F, ws + 65536, rh, cq, lane, acc);
  float cv0 = b2[64 * cq + ln],      cv1 = b2[64 * cq + 16 + ln];
  float cv2 = b2[64 * cq + 32 + ln], cv3 = b2[64 * cq + 48 + ln];
  __syncthreads();  // all H reads complete before overwriting F with Q
#pragma unroll
  for (int ct = 0; ct < 4; ++ct) {
    float bv = (ct == 0) ? cv0 : (ct == 1) ? cv1 : (ct == 2) ? cv2 : cv3;
    int ki2 = 2 * cq + (ct >> 1);
    int g2 = 2 * (ct & 1) + (ln >> 3);
#pragma unroll
    for (int rt = 0; rt < 4; ++rt) {
      int rtg = 4 * rh + rt;
#pragma unroll
      for (int ri = 0; ri < 4; ++ri) {
        int lane2 = g2 * 16 + 4 * g + ri;
        sm.F[(((ki2 * 8 + rtg) * 64 + lane2) << 3) | (ln & 7)] =
            f2bf(acc[rt][ct][ri] + bv);
      }
    }
  }
  __syncthreads();

  // ---- cdist: each wave does 16 row-norms (tile w) + one dot tile ----
  {
    float s = 0.f;
#pragma unroll
    for (int ki = 0; ki < 8; ++ki) {
      short8 v = *reinterpret_cast<const short8*>(
          &sm.F[(((ki * 8 + w) * 64 + lane) << 3)]);
#pragma unroll
      for (int i = 0; i < 8; ++i) {
        float f = bf2f((u16)v[i]);
        s = fmaf(f, f, s);
      }
    }
    s += __shfl_xor(s, 16);  // sum k-groups g (same row, different k slice)
    s += __shfl_xor(s, 32);
    if (lane < 16) sm.nrm[w * 16 + lane] = s;  // row = 16w + ln
  }
  const int P = w >> 2, mt = (w >> 1) & 1, nt = w & 1;
  f32x4 dacc = f32x4{0.f, 0.f, 0.f, 0.f};
  __builtin_amdgcn_s_setprio(1);
#pragma unroll
  for (int ki = 0; ki < 8; ++ki) {
    // A = q tile (4P+mt); B = r tile (4P+2+nt) — A-frag of r IS B-frag of r^T
    short8 aq = *reinterpret_cast<const short8*>(
        &sm.F[(((ki * 8 + 4 * P + mt) * 64 + lane) << 3)]);
    short8 br = *reinterpret_cast<const short8*>(
        &sm.F[(((ki * 8 + 4 * P + 2 + nt) * 64 + lane) << 3)]);
    dacc = MFMA(aq, br, dacc);
  }
  __builtin_amdgcn_s_setprio(0);
  __syncthreads();  // nrm published, all dot reads done

  if (pb + P < Bn) {
    float* Cp = CO + (size_t)(pb + P) * 1024;
#pragma unroll
    for (int ri = 0; ri < 4; ++ri) {
      int k = mt * 16 + 4 * g + ri;   // D layout: row = 4g+ri, col = ln
      int m = nt * 16 + ln;
      float sq = sm.nrm[64 * P + k] + sm.nrm[64 * P + 32 + m] - 2.0f * dacc[ri];
      Cp[k * 32 + m] = sqrtf(fmaxf(sq, 0.0f));
    }
  }
}

// ---------------- kernel B: 1 wave = 1 problem, no barriers ----------------
__global__ __launch_bounds__(256, 4) void sinkhorn_mesh(
    const float* __restrict__ CO, float* __restrict__ simO,
    float* __restrict__ TO, float* __restrict__ costO, int Bn) {
  __shared__ float Wl[4][32 * 33];
  __shared__ float ABl[4][64];
  const int wv = threadIdx.x >> 6, lane = threadIdx.x & 63;
  const int p = blockIdx.x * 4 + wv;
  if (p >= Bn) return;
  const int h = lane >> 5, q = lane & 31;  // q = row k (row ops) / col (col ops)
  float* Wm = Wl[wv];
  float* LA = ABl[wv];
  float* LB = ABl[wv] + 32;
  const float* Cp = CO + (size_t)p * 1024;

  // lane holds row q cols [16h,16h+16) in lkr, col q rows [16h,16h+16) in lkc
  float lkr[16], lkc[16];
#pragma unroll
  for (int jj = 0; jj < 4; ++jj) {
    f32x4 v = *reinterpret_cast<const f32x4*>(Cp + q * 32 + h * 16 + jj * 4);
    int base = q * 33 + h * 16 + jj * 4;
    Wm[base + 0] = v[0]; Wm[base + 1] = v[1]; Wm[base + 2] = v[2]; Wm[base + 3] = v[3];
    lkr[jj * 4 + 0] = -20.f * v[0]; lkr[jj * 4 + 1] = -20.f * v[1];
    lkr[jj * 4 + 2] = -20.f * v[2]; lkr[jj * 4 + 3] = -20.f * v[3];
  }
  LB[q] = 0.0f;
  __builtin_amdgcn_wave_barrier();
#pragma unroll
  for (int j = 0; j < 16; ++j) lkc[j] = -20.f * Wm[(h * 16 + j) * 33 + q];

  for (int it = 0; it < 15; ++it) {
    float v[16], mx, s;
#pragma unroll
    for (int j = 0; j < 16; ++j) v[j] = lkr[j] + LB[h * 16 + j];
    mx = v[0];
#pragma unroll
    for (int j = 1; j < 16; ++j) mx = fmaxf(mx, v[j]);
    mx = fmaxf(mx, __shfl_xor(mx, 32));
    s = 0.f;
#pragma unroll
    for (int j = 0; j < 16; ++j) s += __expf(v[j] - mx);
    s += __shfl_xor(s, 32);
    LA[q] = -(mx + __logf(s));  // both halves write identical value
    __builtin_amdgcn_wave_barrier();
#pragma unroll
    for (int j = 0; j < 16; ++j) v[j] = lkc[j] + LA[h * 16 + j];
    mx = v[0];
#pragma unroll
    for (int j = 1; j < 16; ++j) mx = fmaxf(mx, v[j]);
    mx = fmaxf(mx, __shfl_xor(mx, 32));
    s = 0.f;
#pragma unroll
    for (int j = 0; j < 16; ++j) s += __expf(v[j] - mx);
    s += __shfl_xor(s, 32);
    LB[q] = -(mx + __logf(s));
    __builtin_amdgcn_wave_barrier();
  }

  // T = exp(log_K + la + lb), row view
  float t[16];
  {
    float la = LA[q];
#pragma unroll
    for (int j = 0; j < 16; ++j) t[j] = __expf(lkr[j] + la + LB[h * 16 + j]);
  }

  // mesh: T=T^2; row-norm; col-norm (via LDS transpose; wave-sync only)
  for (int mi = 0; mi < 3; ++mi) {
    float s = 0.f;
#pragma unroll
    for (int j = 0; j < 16; ++j) { t[j] *= t[j]; s += t[j]; }
    s += __shfl_xor(s, 32);
    float inv = 1.0f / (s + 1e-8f);
#pragma unroll
    for (int j = 0; j < 16; ++j) Wm[q * 33 + h * 16 + j] = t[j] * inv;
    __builtin_amdgcn_wave_barrier();
#pragma unroll
    for (int j = 0; j < 16; ++j) t[j] = Wm[(h * 16 + j) * 33 + q];  // col view
    s = 0.f;
#pragma unroll
    for (int j = 0; j < 16; ++j) s += t[j];
    s += __shfl_xor(s, 32);
    inv = 1.0f / (s + 1e-8f);
#pragma unroll
    for (int j = 0; j < 16; ++j) Wm[(h * 16 + j) * 33 + q] = t[j] * inv;
    __builtin_amdgcn_wave_barrier();
#pragma unroll
    for (int j = 0; j < 16; ++j) t[j] = Wm[q * 33 + h * 16 + j];  // back to rows
  }

  // cost = sum(T*C); C = -lkr/20
  float pp = 0.f;
#pragma unroll
  for (int j = 0; j < 16; ++j) pp = fmaf(t[j], -0.05f * lkr[j], pp);
  pp += __shfl_xor(pp, 1); pp += __shfl_xor(pp, 2); pp += __shfl_xor(pp, 4);
  pp += __shfl_xor(pp, 8); pp += __shfl_xor(pp, 16); pp += __shfl_xor(pp, 32);
  if (lane == 0) {
    costO[p] = pp;
    simO[p] = 1.0f / (1.0f + __expf(pp));  // sigmoid(-cost)
  }
  // T out (coalesced, written once never re-read -> nontemporal)
#pragma unroll
  for (int jj = 0; jj < 4; ++jj) {
    f32x4 o;
    o[0] = t[jj * 4 + 0]; o[1] = t[jj * 4 + 1];
    o[2] = t[jj * 4 + 2]; o[3] = t[jj * 4 + 3];
    __builtin_nontemporal_store(
        o, reinterpret_cast<f32x4*>(TO + (size_t)p * 1024 + q * 32 + h * 16 + jj * 4));
  }
}

extern "C" void kernel_launch(void* const* d_in, const int* in_sizes, int n_in,
                              void* d_out, int out_size, void* d_ws, size_t ws_size,
                              hipStream_t stream) {
  const float* slots_q = (const float*)d_in[0];
  const float* slots_r = (const float*)d_in[1];
  const float* W1 = (const float*)d_in[2];
  const float* b1 = (const float*)d_in[3];
  const float* W2 = (const float*)d_in[4];
  const float* b2 = (const float*)d_in[5];
  float* out = (float*)d_out;

  const int Bn = in_sizes[0] / 8192;  // 32*256 per batch element
  u16* ws = (u16*)d_ws;               // 256 KB W fragments

  prep_w<<<dim3(512), dim3(256), 0, stream>>>(W1, W2, ws);

  float* simO = out;
  float* TO = out + Bn;
  float* CO = TO + (size_t)Bn * 1024;
  float* costO = CO + (size_t)Bn * 1024;

  gemm_cdist2<<<dim3((Bn + 1) / 2), dim3(512), 0, stream>>>(slots_q, slots_r,
                                                            b1, b2, ws, CO, Bn);
  sinkhorn_mesh<<<dim3((Bn + 3) / 4), dim3(256), 0, stream>>>(CO, simO, TO, costO, Bn);
}